// Round 9
// baseline (79.822 us; speedup 1.0000x reference)
//
#include <hip/hip_runtime.h>

// SuperPointMatchesGenerator: B=8, N0=N1=2048 mutual-NN under homography.
// d_out f32, concat: gt_matches0[8,2048] | gt_matches1[8,2048] | min_dist0[8,2048]
//
// R18 = VERBATIM R15 RESTORE (proven PASS @ 78.9us, absmax 0.125, round 6).
// R17 post-mortem: FMA inner loop FAILED (absmax 1617) -> the "FP slack"
// theory is REFUTED. The 58.56 threshold tolerates only min_dist0 wiggle,
// never an argmin flip (one flip => error ~|i-j| ~ O(700)). d2 has
// catastrophic cancellation (operands ~1.2e6, ulp ~0.125): FMA re-rounding
// perturbs d2 by ~0.1-0.5 and the data HAS top-2 gaps that small. The 8-op
// chain below is BITWISE equal to numpy's: rn(2X*x) = 2*rn(X*x) (scaling
// commutes with RN) => rn(rx2*x + ry2*y) = 2*ab_np; d2 = rn(rn(a2+b2) - 2ab)
// matches np exactly. EXACTNESS IS A HARD CONSTRAINT - do not touch the
// value chain. (Also banked: cooperative fusion dead, 257us grid.sync;
// grid must be 2048 = 2*HGRID.)
//
// Structure: prep (reproject k0 -> q0; k1+|.|^2 -> q1, ws), main 2048 blocks
// (16 rows/block, candidates staged once in 32KB LDS, hoisted 8x
// ds_read_b128, 8-op/pair exact body, u64 keep-first argmin, LDS-transpose
// reduction), final (gather cross-check).
// Keep-first argmin: u64 (d2bits<<32|idx) min; per-thread candidates ascend;
// strict < at every level => smallest index among equal d2.
//
// ws (full path, 576KB): q0 f4[16K] | q1 f4[16K] | gt0p u16[16K] | gt1 u16[16K]
// Fallback (ws < needed): R5-proven 64KB brute force.

#define SPN 2048
#define SPT 16384
#define HGRID (SPT / 16)  // 1024 blocks per mode, 16 rows/block

__device__ __forceinline__ void sp_reproject(const float* __restrict__ T, int b,
                                             float x, float y,
                                             float& X, float& Y, float& S) {
  const float* H = T + b * 9;
  float p0 = __fadd_rn(__fadd_rn(__fmul_rn(H[0], x), __fmul_rn(H[1], y)), H[2]);
  float p1 = __fadd_rn(__fadd_rn(__fmul_rn(H[3], x), __fmul_rn(H[4], y)), H[5]);
  float p2 = __fadd_rn(__fadd_rn(__fmul_rn(H[6], x), __fmul_rn(H[7], y)), H[8]);
  float den = __fadd_rn(p2, 1e-8f);
  X = __fdiv_rn(p0, den);
  Y = __fdiv_rn(p1, den);
  S = __fadd_rn(__fmul_rn(X, X), __fmul_rn(Y, Y));
}

__global__ __launch_bounds__(256) void sp_prep(
    const float2* __restrict__ k0, const float2* __restrict__ k1,
    const float* __restrict__ T, float4* __restrict__ q0, float4* __restrict__ q1) {
  int t = blockIdx.x * 256 + threadIdx.x;
  if (t < SPT) {
    float2 p = k0[t];
    float X, Y, S;
    sp_reproject(T, t >> 11, p.x, p.y, X, Y, S);
    q0[t] = make_float4(X, Y, S, 0.0f);
  } else {
    int u = t - SPT;
    float2 p = k1[u];
    float S = __fadd_rn(__fmul_rn(p.x, p.x), __fmul_rn(p.y, p.y));
    q1[u] = make_float4(p.x, p.y, S, 0.0f);
  }
}

__global__ __launch_bounds__(256, 4) void SuperPointMatchesGenerator_56925496541369_kernel(
    const float4* __restrict__ q0, const float4* __restrict__ q1,
    unsigned short* __restrict__ gt0p, unsigned short* __restrict__ gt1,
    float* __restrict__ out_mind) {
  __shared__ float4 cand[SPN];                    // 32KB; reused for keys later
  const int tid = threadIdx.x;
  const bool m1 = blockIdx.x >= HGRID;            // block-uniform
  const int base = (m1 ? blockIdx.x - HGRID : blockIdx.x) << 4;  // 16 rows
  const int b = base >> 11, cb = b << 11;
  const float4* __restrict__ qr = m1 ? q1 : q0;   // rows
  const float4* __restrict__ qc = (m1 ? q0 : q1) + cb;  // candidates

  // ---- stage 2048 candidates into LDS (8 loads in flight, one drain) ----
  float4 stage[8];
#pragma unroll
  for (int k = 0; k < 8; k++) stage[k] = qc[(k << 8) + tid];
#pragma unroll
  for (int k = 0; k < 8; k++) cand[(k << 8) + tid] = stage[k];

  // ---- row constants (block-uniform -> SGPR broadcast) ----
  float rx2[16], ry2[16], rsv[16], bv[16];
  int bi[16];
#pragma unroll
  for (int r = 0; r < 16; r++) {
    float4 v = qr[base + r];
    rx2[r] = __fmul_rn(2.0f, v.x);                // exact x2
    ry2[r] = __fmul_rn(2.0f, v.y);
    rsv[r] = v.z;
    bv[r] = INFINITY; bi[r] = 0;
  }
  __syncthreads();

  // ---- all 8 ds_read_b128 hoisted, then exact 8-op/pair body ----
  float4 vv[8];
#pragma unroll
  for (int k = 0; k < 8; k++) vv[k] = cand[(k << 8) + tid];
#pragma unroll
  for (int k = 0; k < 8; k++) {
    const int c = (k << 8) + tid;                 // ascending per thread
#pragma unroll
    for (int r = 0; r < 16; r++) {
      float tw = __fadd_rn(__fmul_rn(rx2[r], vv[k].x), __fmul_rn(ry2[r], vv[k].y));
      float s  = __fadd_rn(rsv[r], vv[k].z);
      float d2 = __fsub_rn(s, tw);
      if (d2 < bv[r]) { bv[r] = d2; bi[r] = c; }
    }
  }
  __syncthreads();                                // all cand reads done

  // ---- transpose reduction: keys[16][256] reuse the staging LDS ----
  unsigned long long* keys = (unsigned long long*)cand;
#pragma unroll
  for (int r = 0; r < 16; r++) {
    float dm = fmaxf(bv[r], 0.0f);                // clamp once (see header)
    keys[(r << 8) + tid] =
        ((unsigned long long)__float_as_uint(dm) << 32) | (unsigned)bi[r];
  }
  __syncthreads();

  const int wv = tid >> 6, ln = tid & 63;
#pragma unroll
  for (int rr = 0; rr < 4; rr++) {
    const int r = (wv << 2) + rr;                 // wave wv owns rows 4wv..4wv+3
    unsigned long long k0 = keys[(r << 8) + ln];
    unsigned long long t;
    t = keys[(r << 8) + 64 + ln];  if (t < k0) k0 = t;
    t = keys[(r << 8) + 128 + ln]; if (t < k0) k0 = t;
    t = keys[(r << 8) + 192 + ln]; if (t < k0) k0 = t;
#pragma unroll
    for (int off = 32; off > 0; off >>= 1) {
      unsigned long long o = __shfl_down(k0, off);
      if (o < k0) k0 = o;
    }
    if (ln == 0) {
      int idx = (int)(k0 & 0x7ffu);
      if (!m1) {
        float e = __fsqrt_rn(__uint_as_float((unsigned)(k0 >> 32)));
        unsigned short pk = (unsigned short)idx;
        if (e > 3.0f) pk |= 0x8000u;              // strict >, exact fp32
        gt0p[base + r] = pk;
        out_mind[base + r] = e;
      } else {
        gt1[base + r] = (unsigned short)idx;
      }
    }
  }
}

__global__ __launch_bounds__(256) void SuperPointMatchesGenerator_56925496541369_final(
    const unsigned short* __restrict__ gt0p, const unsigned short* __restrict__ gt1,
    float* __restrict__ out) {
  int t = blockIdx.x * 256 + threadIdx.x;
  if (t >= SPT) return;
  int b = t >> 11, i = t & 2047, cb = b << 11;

  unsigned short p0 = gt0p[t];
  int m0 = p0 & 0x7ff;
  bool ok0 = ((p0 & 0x8000u) == 0) && ((int)gt1[cb + m0] == i);
  out[t] = ok0 ? (float)m0 : -1.0f;

  int istar = gt1[t];                              // gather form of the scatter
  unsigned short ps = gt0p[cb + istar];
  bool ok1 = (((int)(ps & 0x7ff)) == i) && ((ps & 0x8000u) == 0);
  out[SPT + t] = ok1 ? (float)istar : -1.0f;
}

// ---------- fallback (R5-proven, 64KB ws) ----------
__global__ __launch_bounds__(256) void sp_fb_main(
    const float2* __restrict__ k0, const float2* __restrict__ k1,
    const float* __restrict__ T, unsigned short* __restrict__ gt0p,
    unsigned short* __restrict__ gt1, float* __restrict__ out_mind) {
  const bool mode1 = blockIdx.x >= SPN;
  const int base = (mode1 ? blockIdx.x - SPN : blockIdx.x) * 8;
  const int b = base >> 11, cb = b << 11;
  float rx[8], ry[8], rs[8], bv[8];
  int bi[8];
#pragma unroll
  for (int r = 0; r < 8; r++) { bv[r] = INFINITY; bi[r] = 0; }
  if (!mode1) {
#pragma unroll
    for (int r = 0; r < 8; r++) {
      float2 p = k0[base + r];
      sp_reproject(T, b, p.x, p.y, rx[r], ry[r], rs[r]);
    }
    for (int c = threadIdx.x; c < SPN; c += 256) {
      float2 p = k1[cb + c];
      float b2 = __fadd_rn(__fmul_rn(p.x, p.x), __fmul_rn(p.y, p.y));
#pragma unroll
      for (int r = 0; r < 8; r++) {
        float ab = __fadd_rn(__fmul_rn(rx[r], p.x), __fmul_rn(ry[r], p.y));
        float d2 = __fsub_rn(__fadd_rn(rs[r], b2), __fmul_rn(2.0f, ab));
        float dm = fmaxf(d2, 0.0f);
        if (dm < bv[r]) { bv[r] = dm; bi[r] = c; }
      }
    }
  } else {
#pragma unroll
    for (int r = 0; r < 8; r++) {
      float2 p = k1[base + r];
      rx[r] = p.x; ry[r] = p.y;
      rs[r] = __fadd_rn(__fmul_rn(p.x, p.x), __fmul_rn(p.y, p.y));
    }
    for (int c = threadIdx.x; c < SPN; c += 256) {
      float2 p = k0[cb + c];
      float cx, cy, a2;
      sp_reproject(T, b, p.x, p.y, cx, cy, a2);
#pragma unroll
      for (int r = 0; r < 8; r++) {
        float ab = __fadd_rn(__fmul_rn(rx[r], cx), __fmul_rn(ry[r], cy));
        float d2 = __fsub_rn(__fadd_rn(a2, rs[r]), __fmul_rn(2.0f, ab));
        float dm = fmaxf(d2, 0.0f);
        if (dm < bv[r]) { bv[r] = dm; bi[r] = c; }
      }
    }
  }
  unsigned long long key[8];
#pragma unroll
  for (int r = 0; r < 8; r++)
    key[r] = ((unsigned long long)__float_as_uint(bv[r]) << 32) | (unsigned)bi[r];
#pragma unroll
  for (int off = 32; off > 0; off >>= 1) {
#pragma unroll
    for (int r = 0; r < 8; r++) {
      unsigned long long o = __shfl_down(key[r], off);
      if (o < key[r]) key[r] = o;
    }
  }
  __shared__ unsigned long long part[4][8];
  if ((threadIdx.x & 63) == 0) {
    int w = threadIdx.x >> 6;
#pragma unroll
    for (int r = 0; r < 8; r++) part[w][r] = key[r];
  }
  __syncthreads();
  if (threadIdx.x < 8) {
    int r = threadIdx.x;
    unsigned long long k = part[0][r];
#pragma unroll
    for (int w = 1; w < 4; w++)
      if (part[w][r] < k) k = part[w][r];
    int idx = (int)(k & 0x7ffu);
    if (!mode1) {
      float e = __fsqrt_rn(__uint_as_float((unsigned)(k >> 32)));
      unsigned short pk = (unsigned short)idx;
      if (e > 3.0f) pk |= 0x8000u;
      gt0p[base + r] = pk;
      out_mind[base + r] = e;
    } else {
      gt1[base + r] = (unsigned short)idx;
    }
  }
}

extern "C" void kernel_launch(void* const* d_in, const int* in_sizes, int n_in,
                              void* d_out, int out_size, void* d_ws, size_t ws_size,
                              hipStream_t stream) {
  (void)in_sizes; (void)n_in; (void)out_size;
  const float2* k0 = (const float2*)d_in[0];
  const float2* k1 = (const float2*)d_in[1];
  const float* T   = (const float*)d_in[2];
  float* out = (float*)d_out;

  const size_t need = (size_t)2 * SPT * sizeof(float4) + (size_t)2 * SPT * sizeof(unsigned short);
  if (ws_size >= need) {
    float4* q0 = (float4*)d_ws;                          // 256 KB
    float4* q1 = q0 + SPT;                               // 256 KB
    unsigned short* gt0p = (unsigned short*)(q1 + SPT);  // 32 KB
    unsigned short* gt1  = gt0p + SPT;                   // 32 KB
    sp_prep<<<2 * SPT / 256, 256, 0, stream>>>(k0, k1, T, q0, q1);
    SuperPointMatchesGenerator_56925496541369_kernel<<<2 * HGRID, 256, 0, stream>>>(
        q0, q1, gt0p, gt1, out + 2 * SPT);
    SuperPointMatchesGenerator_56925496541369_final<<<SPT / 256, 256, 0, stream>>>(
        gt0p, gt1, out);
  } else {
    unsigned short* gt0p = (unsigned short*)d_ws;
    unsigned short* gt1  = gt0p + SPT;
    sp_fb_main<<<2 * SPN, 256, 0, stream>>>(k0, k1, T, gt0p, gt1, out + 2 * SPT);
    SuperPointMatchesGenerator_56925496541369_final<<<SPT / 256, 256, 0, stream>>>(
        gt0p, gt1, out);
  }
}

// Round 10
// 78.708 us; speedup vs baseline: 1.0142x; 1.0142x over previous
//
#include <hip/hip_runtime.h>

// SuperPointMatchesGenerator: B=8, N0=N1=2048 mutual-NN under homography.
// d_out f32, concat: gt_matches0[8,2048] | gt_matches1[8,2048] | min_dist0[8,2048]
//
// R19 = R18 (proven PASS, 79.8us) + two codegen-only changes:
//  1) #pragma clang fp contract(off) FILE-WIDE. HIP defaults to
//     -ffp-contract=fast and __f*_rn lower to plain fadd/fmul IR -> the
//     backend MAY contract fadd(fmul,fmul) into fma depending on context.
//     R17 proved such contraction flips argmins (absmax 1617). R11/R12's
//     identical-1881 failures are best explained by context-dependent
//     contraction of the relocated staging chain (rule: co-compiled kernel
//     changes perturb codegen). contract(off) makes bit-exactness
//     GUARANTEED, not contingent. No-op for an uncontracted build.
//  2) main __launch_bounds__ (256,4) -> (256,3): VGPR cap 128 -> ~168.
//     Main's live set (rx2/ry2/rsv 48 + bv/bi 32 + vv 32 + staging) ~115-130
//     regs but compiler allocated only 56-64 -> state shuffled through
//     AGPR/remat, matching R13's PMC (VALUBusy 80% = ~2.5x the useful-op
//     volume: 81.4K busy vs 32.7K useful SIMD-cycles). 168 regs lets hot
//     state live architecturally; 32KB LDS still gives >=3 blocks/CU
//     (12 waves/CU), ample for the VALU-bound unrolled body.
// Value chain is UNTOUCHED (hard constraint from R17: threshold 58.56
// tolerates only min_dist0 wiggle, never an argmin flip; d2 has catastrophic
// cancellation, ulp(1.2e6)~0.125).
//
// Banked: cooperative fusion dead (257us grid.sync); direct-input fusion
// dead (contraction); grid must be 2048 = 2*HGRID; exact 8-op chain:
//   p_i=(H0x+H1y)+H2; X=p0/(p2+1e-8); a2=XX+YY;
//   tw=rn(rx2*x+ry2*y) [rx2=2X exact]; d2=rn(rn(a2+b2)-tw);
//   e=sqrt(max(d2,0)) clamped at key-pack.
// Keep-first argmin: u64 (d2bits<<32|idx) min; candidates ascend per thread;
// strict < at every level => smallest index among equal d2 (order-free min).
//
// ws (full path, 576KB): q0 f4[16K] | q1 f4[16K] | gt0p u16[16K] | gt1 u16[16K]
// Fallback (ws < needed): R5-proven 64KB brute force.

#pragma clang fp contract(off)

#define SPN 2048
#define SPT 16384
#define HGRID (SPT / 16)  // 1024 blocks per mode, 16 rows/block

__device__ __forceinline__ void sp_reproject(const float* __restrict__ T, int b,
                                             float x, float y,
                                             float& X, float& Y, float& S) {
  const float* H = T + b * 9;
  float p0 = __fadd_rn(__fadd_rn(__fmul_rn(H[0], x), __fmul_rn(H[1], y)), H[2]);
  float p1 = __fadd_rn(__fadd_rn(__fmul_rn(H[3], x), __fmul_rn(H[4], y)), H[5]);
  float p2 = __fadd_rn(__fadd_rn(__fmul_rn(H[6], x), __fmul_rn(H[7], y)), H[8]);
  float den = __fadd_rn(p2, 1e-8f);
  X = __fdiv_rn(p0, den);
  Y = __fdiv_rn(p1, den);
  S = __fadd_rn(__fmul_rn(X, X), __fmul_rn(Y, Y));
}

__global__ __launch_bounds__(256) void sp_prep(
    const float2* __restrict__ k0, const float2* __restrict__ k1,
    const float* __restrict__ T, float4* __restrict__ q0, float4* __restrict__ q1) {
  int t = blockIdx.x * 256 + threadIdx.x;
  if (t < SPT) {
    float2 p = k0[t];
    float X, Y, S;
    sp_reproject(T, t >> 11, p.x, p.y, X, Y, S);
    q0[t] = make_float4(X, Y, S, 0.0f);
  } else {
    int u = t - SPT;
    float2 p = k1[u];
    float S = __fadd_rn(__fmul_rn(p.x, p.x), __fmul_rn(p.y, p.y));
    q1[u] = make_float4(p.x, p.y, S, 0.0f);
  }
}

__global__ __launch_bounds__(256, 3) void SuperPointMatchesGenerator_56925496541369_kernel(
    const float4* __restrict__ q0, const float4* __restrict__ q1,
    unsigned short* __restrict__ gt0p, unsigned short* __restrict__ gt1,
    float* __restrict__ out_mind) {
  __shared__ float4 cand[SPN];                    // 32KB; reused for keys later
  const int tid = threadIdx.x;
  const bool m1 = blockIdx.x >= HGRID;            // block-uniform
  const int base = (m1 ? blockIdx.x - HGRID : blockIdx.x) << 4;  // 16 rows
  const int b = base >> 11, cb = b << 11;
  const float4* __restrict__ qr = m1 ? q1 : q0;   // rows
  const float4* __restrict__ qc = (m1 ? q0 : q1) + cb;  // candidates

  // ---- stage 2048 candidates into LDS (8 loads in flight, one drain) ----
  float4 stage[8];
#pragma unroll
  for (int k = 0; k < 8; k++) stage[k] = qc[(k << 8) + tid];
#pragma unroll
  for (int k = 0; k < 8; k++) cand[(k << 8) + tid] = stage[k];

  // ---- row constants (block-uniform -> broadcast) ----
  float rx2[16], ry2[16], rsv[16], bv[16];
  int bi[16];
#pragma unroll
  for (int r = 0; r < 16; r++) {
    float4 v = qr[base + r];
    rx2[r] = __fmul_rn(2.0f, v.x);                // exact x2
    ry2[r] = __fmul_rn(2.0f, v.y);
    rsv[r] = v.z;
    bv[r] = INFINITY; bi[r] = 0;
  }
  __syncthreads();

  // ---- all 8 ds_read_b128 hoisted, then exact 8-op/pair body ----
  float4 vv[8];
#pragma unroll
  for (int k = 0; k < 8; k++) vv[k] = cand[(k << 8) + tid];
#pragma unroll
  for (int k = 0; k < 8; k++) {
    const int c = (k << 8) + tid;                 // ascending per thread
#pragma unroll
    for (int r = 0; r < 16; r++) {
      float tw = __fadd_rn(__fmul_rn(rx2[r], vv[k].x), __fmul_rn(ry2[r], vv[k].y));
      float s  = __fadd_rn(rsv[r], vv[k].z);
      float d2 = __fsub_rn(s, tw);
      if (d2 < bv[r]) { bv[r] = d2; bi[r] = c; }
    }
  }
  __syncthreads();                                // all cand reads done

  // ---- transpose reduction: keys[16][256] reuse the staging LDS ----
  unsigned long long* keys = (unsigned long long*)cand;
#pragma unroll
  for (int r = 0; r < 16; r++) {
    float dm = fmaxf(bv[r], 0.0f);                // clamp once (see header)
    keys[(r << 8) + tid] =
        ((unsigned long long)__float_as_uint(dm) << 32) | (unsigned)bi[r];
  }
  __syncthreads();

  const int wv = tid >> 6, ln = tid & 63;
#pragma unroll
  for (int rr = 0; rr < 4; rr++) {
    const int r = (wv << 2) + rr;                 // wave wv owns rows 4wv..4wv+3
    unsigned long long k0 = keys[(r << 8) + ln];
    unsigned long long t;
    t = keys[(r << 8) + 64 + ln];  if (t < k0) k0 = t;
    t = keys[(r << 8) + 128 + ln]; if (t < k0) k0 = t;
    t = keys[(r << 8) + 192 + ln]; if (t < k0) k0 = t;
#pragma unroll
    for (int off = 32; off > 0; off >>= 1) {
      unsigned long long o = __shfl_down(k0, off);
      if (o < k0) k0 = o;
    }
    if (ln == 0) {
      int idx = (int)(k0 & 0x7ffu);
      if (!m1) {
        float e = __fsqrt_rn(__uint_as_float((unsigned)(k0 >> 32)));
        unsigned short pk = (unsigned short)idx;
        if (e > 3.0f) pk |= 0x8000u;              // strict >, exact fp32
        gt0p[base + r] = pk;
        out_mind[base + r] = e;
      } else {
        gt1[base + r] = (unsigned short)idx;
      }
    }
  }
}

__global__ __launch_bounds__(256) void SuperPointMatchesGenerator_56925496541369_final(
    const unsigned short* __restrict__ gt0p, const unsigned short* __restrict__ gt1,
    float* __restrict__ out) {
  int t = blockIdx.x * 256 + threadIdx.x;
  if (t >= SPT) return;
  int b = t >> 11, i = t & 2047, cb = b << 11;

  unsigned short p0 = gt0p[t];
  int m0 = p0 & 0x7ff;
  bool ok0 = ((p0 & 0x8000u) == 0) && ((int)gt1[cb + m0] == i);
  out[t] = ok0 ? (float)m0 : -1.0f;

  int istar = gt1[t];                              // gather form of the scatter
  unsigned short ps = gt0p[cb + istar];
  bool ok1 = (((int)(ps & 0x7ff)) == i) && ((ps & 0x8000u) == 0);
  out[SPT + t] = ok1 ? (float)istar : -1.0f;
}

// ---------- fallback (R5-proven, 64KB ws) ----------
__global__ __launch_bounds__(256) void sp_fb_main(
    const float2* __restrict__ k0, const float2* __restrict__ k1,
    const float* __restrict__ T, unsigned short* __restrict__ gt0p,
    unsigned short* __restrict__ gt1, float* __restrict__ out_mind) {
  const bool mode1 = blockIdx.x >= SPN;
  const int base = (mode1 ? blockIdx.x - SPN : blockIdx.x) * 8;
  const int b = base >> 11, cb = b << 11;
  float rx[8], ry[8], rs[8], bv[8];
  int bi[8];
#pragma unroll
  for (int r = 0; r < 8; r++) { bv[r] = INFINITY; bi[r] = 0; }
  if (!mode1) {
#pragma unroll
    for (int r = 0; r < 8; r++) {
      float2 p = k0[base + r];
      sp_reproject(T, b, p.x, p.y, rx[r], ry[r], rs[r]);
    }
    for (int c = threadIdx.x; c < SPN; c += 256) {
      float2 p = k1[cb + c];
      float b2 = __fadd_rn(__fmul_rn(p.x, p.x), __fmul_rn(p.y, p.y));
#pragma unroll
      for (int r = 0; r < 8; r++) {
        float ab = __fadd_rn(__fmul_rn(rx[r], p.x), __fmul_rn(ry[r], p.y));
        float d2 = __fsub_rn(__fadd_rn(rs[r], b2), __fmul_rn(2.0f, ab));
        float dm = fmaxf(d2, 0.0f);
        if (dm < bv[r]) { bv[r] = dm; bi[r] = c; }
      }
    }
  } else {
#pragma unroll
    for (int r = 0; r < 8; r++) {
      float2 p = k1[base + r];
      rx[r] = p.x; ry[r] = p.y;
      rs[r] = __fadd_rn(__fmul_rn(p.x, p.x), __fmul_rn(p.y, p.y));
    }
    for (int c = threadIdx.x; c < SPN; c += 256) {
      float2 p = k0[cb + c];
      float cx, cy, a2;
      sp_reproject(T, b, p.x, p.y, cx, cy, a2);
#pragma unroll
      for (int r = 0; r < 8; r++) {
        float ab = __fadd_rn(__fmul_rn(rx[r], cx), __fmul_rn(ry[r], cy));
        float d2 = __fsub_rn(__fadd_rn(a2, rs[r]), __fmul_rn(2.0f, ab));
        float dm = fmaxf(d2, 0.0f);
        if (dm < bv[r]) { bv[r] = dm; bi[r] = c; }
      }
    }
  }
  unsigned long long key[8];
#pragma unroll
  for (int r = 0; r < 8; r++)
    key[r] = ((unsigned long long)__float_as_uint(bv[r]) << 32) | (unsigned)bi[r];
#pragma unroll
  for (int off = 32; off > 0; off >>= 1) {
#pragma unroll
    for (int r = 0; r < 8; r++) {
      unsigned long long o = __shfl_down(key[r], off);
      if (o < key[r]) key[r] = o;
    }
  }
  __shared__ unsigned long long part[4][8];
  if ((threadIdx.x & 63) == 0) {
    int w = threadIdx.x >> 6;
#pragma unroll
    for (int r = 0; r < 8; r++) part[w][r] = key[r];
  }
  __syncthreads();
  if (threadIdx.x < 8) {
    int r = threadIdx.x;
    unsigned long long k = part[0][r];
#pragma unroll
    for (int w = 1; w < 4; w++)
      if (part[w][r] < k) k = part[w][r];
    int idx = (int)(k & 0x7ffu);
    if (!mode1) {
      float e = __fsqrt_rn(__uint_as_float((unsigned)(k >> 32)));
      unsigned short pk = (unsigned short)idx;
      if (e > 3.0f) pk |= 0x8000u;
      gt0p[base + r] = pk;
      out_mind[base + r] = e;
    } else {
      gt1[base + r] = (unsigned short)idx;
    }
  }
}

extern "C" void kernel_launch(void* const* d_in, const int* in_sizes, int n_in,
                              void* d_out, int out_size, void* d_ws, size_t ws_size,
                              hipStream_t stream) {
  (void)in_sizes; (void)n_in; (void)out_size;
  const float2* k0 = (const float2*)d_in[0];
  const float2* k1 = (const float2*)d_in[1];
  const float* T   = (const float*)d_in[2];
  float* out = (float*)d_out;

  const size_t need = (size_t)2 * SPT * sizeof(float4) + (size_t)2 * SPT * sizeof(unsigned short);
  if (ws_size >= need) {
    float4* q0 = (float4*)d_ws;                          // 256 KB
    float4* q1 = q0 + SPT;                               // 256 KB
    unsigned short* gt0p = (unsigned short*)(q1 + SPT);  // 32 KB
    unsigned short* gt1  = gt0p + SPT;                   // 32 KB
    sp_prep<<<2 * SPT / 256, 256, 0, stream>>>(k0, k1, T, q0, q1);
    SuperPointMatchesGenerator_56925496541369_kernel<<<2 * HGRID, 256, 0, stream>>>(
        q0, q1, gt0p, gt1, out + 2 * SPT);
    SuperPointMatchesGenerator_56925496541369_final<<<SPT / 256, 256, 0, stream>>>(
        gt0p, gt1, out);
  } else {
    unsigned short* gt0p = (unsigned short*)d_ws;
    unsigned short* gt1  = gt0p + SPT;
    sp_fb_main<<<2 * SPN, 256, 0, stream>>>(k0, k1, T, gt0p, gt1, out + 2 * SPT);
    SuperPointMatchesGenerator_56925496541369_final<<<SPT / 256, 256, 0, stream>>>(
        gt0p, gt1, out);
  }
}